// Round 1
// baseline (434.997 us; speedup 1.0000x reference)
//
#include <hip/hip_runtime.h>

#define IN_F 256
#define OUT_F 64

// ---------------------------------------------------------------------------
// Stage 1: degree histograms. deg_out[src[e]] += 1, deg_in[dst[e]] += 1.
// ---------------------------------------------------------------------------
__global__ __launch_bounds__(256) void k_degrees(const int* __restrict__ src,
                                                 const int* __restrict__ dst,
                                                 float* __restrict__ deg_out,
                                                 float* __restrict__ deg_in,
                                                 int ne) {
    int e = blockIdx.x * 256 + threadIdx.x;
    if (e < ne) {
        atomicAdd(&deg_out[src[e]], 1.0f);
        atomicAdd(&deg_in[dst[e]], 1.0f);
    }
}

// ---------------------------------------------------------------------------
// Stage 2: h = diag(rsqrt(max(deg_out,1))) * X * W        [n x 64]
// Block: 256 threads, 64 rows/block. k-chunked LDS staging (W chunk + X tile).
// Thread (r = tid>>2, c = tid&3) computes row r, feats c*16 .. c*16+15.
// ---------------------------------------------------------------------------
__global__ __launch_bounds__(256) void k_gemm(const float* __restrict__ x,
                                              const float* __restrict__ W,
                                              const float* __restrict__ deg_out,
                                              float* __restrict__ h, int n) {
    constexpr int R = 64;          // rows per block
    constexpr int KC = 64;         // k chunk
    constexpr int XPAD = KC + 4;   // pad -> 2-way-max LDS bank aliasing (free)
    __shared__ float sw[KC * OUT_F];   // 16 KB
    __shared__ float sx[R * XPAD];     // 17 KB

    const int tid = threadIdx.x;
    const int r = tid >> 2;
    const int c = tid & 3;
    const int row0 = blockIdx.x * R;
    const int row = row0 + r;

    float acc[16];
#pragma unroll
    for (int j = 0; j < 16; ++j) acc[j] = 0.0f;

    for (int kc = 0; kc < IN_F; kc += KC) {
        // stage W chunk: KC x 64 floats, contiguous; 4 float4 per thread
#pragma unroll
        for (int i = 0; i < (KC * OUT_F) / (256 * 4); ++i) {
            int idx = (tid + i * 256) * 4;
            *(float4*)&sw[idx] = *(const float4*)&W[(size_t)kc * OUT_F + idx];
        }
        // stage X tile: R x KC floats; float4 per lane, coalesced along k
#pragma unroll
        for (int j = tid; j < R * (KC / 4); j += 256) {
            int rr = j >> 4;             // 0..63
            int cc = (j & 15) * 4;       // 0..60
            int grow = row0 + rr;
            float4 v = make_float4(0.f, 0.f, 0.f, 0.f);
            if (grow < n) v = *(const float4*)&x[(size_t)grow * IN_F + kc + cc];
            *(float4*)&sx[rr * XPAD + cc] = v;
        }
        __syncthreads();

#pragma unroll 8
        for (int k = 0; k < KC; ++k) {
            float xv = sx[r * XPAD + k];
            const float4* wrow = (const float4*)&sw[k * OUT_F + c * 16];
            float4 w0 = wrow[0], w1 = wrow[1], w2 = wrow[2], w3 = wrow[3];
            acc[0]  += xv * w0.x; acc[1]  += xv * w0.y;
            acc[2]  += xv * w0.z; acc[3]  += xv * w0.w;
            acc[4]  += xv * w1.x; acc[5]  += xv * w1.y;
            acc[6]  += xv * w1.z; acc[7]  += xv * w1.w;
            acc[8]  += xv * w2.x; acc[9]  += xv * w2.y;
            acc[10] += xv * w2.z; acc[11] += xv * w2.w;
            acc[12] += xv * w3.x; acc[13] += xv * w3.y;
            acc[14] += xv * w3.z; acc[15] += xv * w3.w;
        }
        __syncthreads();
    }

    if (row < n) {
        float s = rsqrtf(fmaxf(deg_out[row], 1.0f));
        float* hp = &h[(size_t)row * OUT_F + c * 16];
#pragma unroll
        for (int q = 0; q < 4; ++q) {
            float4 v = make_float4(acc[q * 4 + 0] * s, acc[q * 4 + 1] * s,
                                   acc[q * 4 + 2] * s, acc[q * 4 + 3] * s);
            *(float4*)&hp[q * 4] = v;
        }
    }
}

// ---------------------------------------------------------------------------
// Stage 3: edge-parallel scatter-add: out[dst[e]][f] += h[src[e]][f]
// One 64-lane wave per edge; lane = feature. 4 edges per 256-thread block.
// ---------------------------------------------------------------------------
__global__ __launch_bounds__(256) void k_agg(const int* __restrict__ src,
                                             const int* __restrict__ dst,
                                             const float* __restrict__ h,
                                             float* __restrict__ out, int ne) {
    int e = blockIdx.x * 4 + (threadIdx.x >> 6);
    int f = threadIdx.x & 63;
    if (e < ne) {
        int s = src[e];
        int d = dst[e];
        float v = h[(size_t)s * OUT_F + f];
        atomicAdd(&out[(size_t)d * OUT_F + f], v);
    }
}

// ---------------------------------------------------------------------------
// Stage 4: out = out * rsqrt(max(deg_in,1)) + b
// ---------------------------------------------------------------------------
__global__ __launch_bounds__(256) void k_finalize(float* __restrict__ out,
                                                  const float* __restrict__ deg_in,
                                                  const float* __restrict__ b,
                                                  int n) {
    int i = blockIdx.x * 256 + threadIdx.x;
    if (i < n * OUT_F) {
        int node = i >> 6;
        int f = i & 63;
        out[i] = out[i] * rsqrtf(fmaxf(deg_in[node], 1.0f)) + b[f];
    }
}

extern "C" void kernel_launch(void* const* d_in, const int* in_sizes, int n_in,
                              void* d_out, int out_size, void* d_ws, size_t ws_size,
                              hipStream_t stream) {
    const float* x   = (const float*)d_in[0];
    const int*   src = (const int*)d_in[1];
    const int*   dst = (const int*)d_in[2];
    const float* W   = (const float*)d_in[3];
    const float* b   = (const float*)d_in[4];
    float* out = (float*)d_out;

    const int n  = in_sizes[0] / IN_F;   // 100000
    const int ne = in_sizes[1];          // 1000000

    float* deg_out = (float*)d_ws;
    float* deg_in  = deg_out + n;
    float* h       = deg_in + n;         // n*64 floats

    hipMemsetAsync(deg_out, 0, 2ull * n * sizeof(float), stream);
    hipMemsetAsync(d_out, 0, (size_t)out_size * sizeof(float), stream);

    k_degrees<<<(ne + 255) / 256, 256, 0, stream>>>(src, dst, deg_out, deg_in, ne);
    k_gemm<<<(n + 63) / 64, 256, 0, stream>>>(x, W, deg_out, h, n);
    k_agg<<<(ne + 3) / 4, 256, 0, stream>>>(src, dst, h, out, ne);
    k_finalize<<<(n * OUT_F + 255) / 256, 256, 0, stream>>>(out, deg_in, b, n);
}

// Round 2
// 295.010 us; speedup vs baseline: 1.4745x; 1.4745x over previous
//
#include <hip/hip_runtime.h>

#define IN_F 256
#define OUT_F 64

// ---------------------------------------------------------------------------
// Stage 1: integer degree histograms.
// ---------------------------------------------------------------------------
__global__ __launch_bounds__(256) void k_hist(const int* __restrict__ src,
                                              const int* __restrict__ dst,
                                              int* __restrict__ deg_out,
                                              int* __restrict__ deg_in,
                                              int ne) {
    int e = blockIdx.x * 256 + threadIdx.x;
    if (e < ne) {
        atomicAdd(&deg_out[src[e]], 1);
        atomicAdd(&deg_in[dst[e]], 1);
    }
}

// ---------------------------------------------------------------------------
// Stage 2: exclusive scan of deg_in -> row_ptr.  n = 100000, 1024 elems/block
// -> 98 blocks of partials (fits one 256-thread block in stage 2).
// ---------------------------------------------------------------------------
__global__ __launch_bounds__(256) void k_scan1(const int* __restrict__ deg,
                                               int* __restrict__ excl,
                                               int* __restrict__ partials, int n) {
    __shared__ int sd[256];
    const int tid = threadIdx.x;
    const int idx = blockIdx.x * 1024 + tid * 4;
    int v0 = 0, v1 = 0, v2 = 0, v3 = 0;
    if (idx     < n) v0 = deg[idx];
    if (idx + 1 < n) v1 = deg[idx + 1];
    if (idx + 2 < n) v2 = deg[idx + 2];
    if (idx + 3 < n) v3 = deg[idx + 3];
    const int tsum = v0 + v1 + v2 + v3;
    sd[tid] = tsum;
    __syncthreads();
    for (int off = 1; off < 256; off <<= 1) {
        int t = (tid >= off) ? sd[tid - off] : 0;
        __syncthreads();
        sd[tid] += t;
        __syncthreads();
    }
    const int texcl = sd[tid] - tsum;
    if (tid == 255) partials[blockIdx.x] = sd[255];
    if (idx     < n) excl[idx]     = texcl;
    if (idx + 1 < n) excl[idx + 1] = texcl + v0;
    if (idx + 2 < n) excl[idx + 2] = texcl + v0 + v1;
    if (idx + 3 < n) excl[idx + 3] = texcl + v0 + v1 + v2;
}

__global__ __launch_bounds__(256) void k_scan2(int* __restrict__ partials, int nb) {
    __shared__ int sd[256];
    const int tid = threadIdx.x;
    const int v = (tid < nb) ? partials[tid] : 0;
    sd[tid] = v;
    __syncthreads();
    for (int off = 1; off < 256; off <<= 1) {
        int t = (tid >= off) ? sd[tid - off] : 0;
        __syncthreads();
        sd[tid] += t;
        __syncthreads();
    }
    if (tid < nb) partials[tid] = sd[tid] - v;  // exclusive
}

__global__ __launch_bounds__(256) void k_scan3(int* __restrict__ excl,
                                               const int* __restrict__ partials, int n) {
    int i = blockIdx.x * 256 + threadIdx.x;
    if (i < n) excl[i] += partials[blockIdx.x >> 2];  // 1024 elems per partial
}

// ---------------------------------------------------------------------------
// Stage 3: scatter edges into dst-sorted order (CSR). 1M int atomics.
// ---------------------------------------------------------------------------
__global__ __launch_bounds__(256) void k_scatter(const int* __restrict__ src,
                                                 const int* __restrict__ dst,
                                                 const int* __restrict__ row_ptr,
                                                 int* __restrict__ cursor,
                                                 int* __restrict__ src_sorted, int ne) {
    int e = blockIdx.x * 256 + threadIdx.x;
    if (e < ne) {
        int d = dst[e];
        int pos = row_ptr[d] + atomicAdd(&cursor[d], 1);
        src_sorted[pos] = src[e];
    }
}

// ---------------------------------------------------------------------------
// Stage 4: h = diag(rsqrt(max(deg_out,1))) * X * W.  64x64 tile, 4x4 microtile.
// ---------------------------------------------------------------------------
__global__ __launch_bounds__(256) void k_gemm(const float* __restrict__ x,
                                              const float* __restrict__ W,
                                              const int* __restrict__ deg_out,
                                              float* __restrict__ h, int n) {
    constexpr int R = 64, KC = 64, XPAD = KC + 4;  // XPAD*4 = 272 B, 16B-aligned
    __shared__ float sw[KC * OUT_F];   // 16 KB
    __shared__ float sx[R * XPAD];     // 17 KB

    const int tid = threadIdx.x;
    const int tx = tid & 15;   // cols tx*4 .. tx*4+3
    const int ty = tid >> 4;   // rows ty*4 .. ty*4+3
    const int row0 = blockIdx.x * R;

    float acc[4][4] = {{0.f}};

    for (int kc = 0; kc < IN_F; kc += KC) {
#pragma unroll
        for (int i = 0; i < 4; ++i) {
            int idx = (tid + i * 256) * 4;
            *(float4*)&sw[idx] = *(const float4*)&W[(size_t)kc * OUT_F + idx];
        }
#pragma unroll
        for (int i = 0; i < 4; ++i) {
            int j = tid + i * 256;
            int rr = j >> 4;
            int cc = (j & 15) * 4;
            int grow = row0 + rr;
            float4 v = make_float4(0.f, 0.f, 0.f, 0.f);
            if (grow < n) v = *(const float4*)&x[(size_t)grow * IN_F + kc + cc];
            *(float4*)&sx[rr * XPAD + cc] = v;
        }
        __syncthreads();

#pragma unroll
        for (int k = 0; k < KC; k += 4) {
            float4 xr[4], wr[4];
#pragma unroll
            for (int i = 0; i < 4; ++i) xr[i] = *(const float4*)&sx[(ty * 4 + i) * XPAD + k];
#pragma unroll
            for (int j = 0; j < 4; ++j) wr[j] = *(const float4*)&sw[(k + j) * OUT_F + tx * 4];
#pragma unroll
            for (int i = 0; i < 4; ++i) {
                acc[i][0] += xr[i].x * wr[0].x + xr[i].y * wr[1].x + xr[i].z * wr[2].x + xr[i].w * wr[3].x;
                acc[i][1] += xr[i].x * wr[0].y + xr[i].y * wr[1].y + xr[i].z * wr[2].y + xr[i].w * wr[3].y;
                acc[i][2] += xr[i].x * wr[0].z + xr[i].y * wr[1].z + xr[i].z * wr[2].z + xr[i].w * wr[3].z;
                acc[i][3] += xr[i].x * wr[0].w + xr[i].y * wr[1].w + xr[i].z * wr[2].w + xr[i].w * wr[3].w;
            }
        }
        __syncthreads();
    }

#pragma unroll
    for (int i = 0; i < 4; ++i) {
        int row = row0 + ty * 4 + i;
        if (row < n) {
            float s = rsqrtf(fmaxf((float)deg_out[row], 1.0f));
            float4 v = make_float4(acc[i][0] * s, acc[i][1] * s, acc[i][2] * s, acc[i][3] * s);
            *(float4*)&h[(size_t)row * OUT_F + tx * 4] = v;
        }
    }
}

// ---------------------------------------------------------------------------
// Stage 5: CSR gather-aggregate + scale + bias. One wave per node, lane=feat.
// ---------------------------------------------------------------------------
__global__ __launch_bounds__(256) void k_aggregate(const int* __restrict__ row_ptr,
                                                   const int* __restrict__ deg_in,
                                                   const int* __restrict__ src_sorted,
                                                   const float* __restrict__ h,
                                                   const float* __restrict__ b,
                                                   float* __restrict__ out, int n) {
    int node = blockIdx.x * 4 + (threadIdx.x >> 6);
    int f = threadIdx.x & 63;
    if (node >= n) return;
    const int start = row_ptr[node];
    const int deg = deg_in[node];
    float acc0 = 0.f, acc1 = 0.f;
    int i = 0;
    for (; i + 1 < deg; i += 2) {
        int s0 = src_sorted[start + i];
        int s1 = src_sorted[start + i + 1];
        acc0 += h[(size_t)s0 * OUT_F + f];
        acc1 += h[(size_t)s1 * OUT_F + f];
    }
    if (i < deg) acc0 += h[(size_t)src_sorted[start + i] * OUT_F + f];
    float scale = rsqrtf(fmaxf((float)deg, 1.0f));
    out[(size_t)node * OUT_F + f] = (acc0 + acc1) * scale + b[f];
}

extern "C" void kernel_launch(void* const* d_in, const int* in_sizes, int n_in,
                              void* d_out, int out_size, void* d_ws, size_t ws_size,
                              hipStream_t stream) {
    const float* x   = (const float*)d_in[0];
    const int*   src = (const int*)d_in[1];
    const int*   dst = (const int*)d_in[2];
    const float* W   = (const float*)d_in[3];
    const float* b   = (const float*)d_in[4];
    float* out = (float*)d_out;

    const int n  = in_sizes[0] / IN_F;   // 100000
    const int ne = in_sizes[1];          // 1000000

    int* deg_out_i  = (int*)d_ws;
    int* deg_in_i   = deg_out_i + n;
    int* cursor     = deg_in_i + n;
    int* row_ptr    = cursor + n;
    int* partials   = row_ptr + n;
    int* src_sorted = partials + 256;
    float* h        = (float*)(src_sorted + ne);

    const int nb_scan = (n + 1023) / 1024;  // 98 (must be <= 256)

    // zero: deg_out_i, deg_in_i, cursor (contiguous)
    hipMemsetAsync(deg_out_i, 0, 3ull * n * sizeof(int), stream);

    k_hist<<<(ne + 255) / 256, 256, 0, stream>>>(src, dst, deg_out_i, deg_in_i, ne);
    k_scan1<<<nb_scan, 256, 0, stream>>>(deg_in_i, row_ptr, partials, n);
    k_scan2<<<1, 256, 0, stream>>>(partials, nb_scan);
    k_scan3<<<(n + 255) / 256, 256, 0, stream>>>(row_ptr, partials, n);
    k_scatter<<<(ne + 255) / 256, 256, 0, stream>>>(src, dst, row_ptr, cursor, src_sorted, ne);
    k_gemm<<<(n + 63) / 64, 256, 0, stream>>>(x, W, deg_out_i, h, n);
    k_aggregate<<<(n + 3) / 4, 256, 0, stream>>>(row_ptr, deg_in_i, src_sorted, h, b, out, n);
}

// Round 4
// 249.121 us; speedup vs baseline: 1.7461x; 1.1842x over previous
//
#include <hip/hip_runtime.h>

#define IN_F 256
#define OUT_F 64

typedef __attribute__((ext_vector_type(8))) short s16x8;
typedef __attribute__((ext_vector_type(4))) float f32x4;

__device__ __forceinline__ unsigned short bf16_rne(float f) {
    unsigned u = __builtin_bit_cast(unsigned, f);
    u += 0x7FFFu + ((u >> 16) & 1u);
    return (unsigned short)(u >> 16);
}
__device__ __forceinline__ float bf16_f(unsigned short u) {
    unsigned v = ((unsigned)u) << 16;
    return __builtin_bit_cast(float, v);
}

// ---------------------------------------------------------------------------
// Stage 1: integer degree histograms.
// ---------------------------------------------------------------------------
__global__ __launch_bounds__(256) void k_hist(const int* __restrict__ src,
                                              const int* __restrict__ dst,
                                              int* __restrict__ deg_out,
                                              int* __restrict__ deg_in,
                                              int ne) {
    int e = blockIdx.x * 256 + threadIdx.x;
    if (e < ne) {
        atomicAdd(&deg_out[src[e]], 1);
        atomicAdd(&deg_in[dst[e]], 1);
    }
}

// ---------------------------------------------------------------------------
// Stage 2: exclusive scan of deg_in -> row_ptr (and cursor copy).
// ---------------------------------------------------------------------------
__global__ __launch_bounds__(256) void k_scan1(const int* __restrict__ deg,
                                               int* __restrict__ excl,
                                               int* __restrict__ partials, int n) {
    __shared__ int sd[256];
    const int tid = threadIdx.x;
    const int idx = blockIdx.x * 1024 + tid * 4;
    int v0 = 0, v1 = 0, v2 = 0, v3 = 0;
    if (idx     < n) v0 = deg[idx];
    if (idx + 1 < n) v1 = deg[idx + 1];
    if (idx + 2 < n) v2 = deg[idx + 2];
    if (idx + 3 < n) v3 = deg[idx + 3];
    const int tsum = v0 + v1 + v2 + v3;
    sd[tid] = tsum;
    __syncthreads();
    for (int off = 1; off < 256; off <<= 1) {
        int t = (tid >= off) ? sd[tid - off] : 0;
        __syncthreads();
        sd[tid] += t;
        __syncthreads();
    }
    const int texcl = sd[tid] - tsum;
    if (tid == 255) partials[blockIdx.x] = sd[255];
    if (idx     < n) excl[idx]     = texcl;
    if (idx + 1 < n) excl[idx + 1] = texcl + v0;
    if (idx + 2 < n) excl[idx + 2] = texcl + v0 + v1;
    if (idx + 3 < n) excl[idx + 3] = texcl + v0 + v1 + v2;
}

__global__ __launch_bounds__(256) void k_scan2(int* __restrict__ partials, int nb) {
    __shared__ int sd[256];
    const int tid = threadIdx.x;
    const int v = (tid < nb) ? partials[tid] : 0;
    sd[tid] = v;
    __syncthreads();
    for (int off = 1; off < 256; off <<= 1) {
        int t = (tid >= off) ? sd[tid - off] : 0;
        __syncthreads();
        sd[tid] += t;
        __syncthreads();
    }
    if (tid < nb) partials[tid] = sd[tid] - v;  // exclusive
}

__global__ __launch_bounds__(256) void k_scan3(int* __restrict__ excl,
                                               int* __restrict__ cursor,
                                               const int* __restrict__ partials, int n) {
    int i = blockIdx.x * 256 + threadIdx.x;
    if (i < n) {
        int v = excl[i] + partials[blockIdx.x >> 2];
        excl[i] = v;
        cursor[i] = v;
    }
}

// ---------------------------------------------------------------------------
// Stage 3: scatter edges into dst-sorted order. cursor pre-seeded = row_ptr.
// ---------------------------------------------------------------------------
__global__ __launch_bounds__(256) void k_scatter(const int* __restrict__ src,
                                                 const int* __restrict__ dst,
                                                 int* __restrict__ cursor,
                                                 int* __restrict__ src_sorted, int ne) {
    int e = blockIdx.x * 256 + threadIdx.x;
    if (e < ne) {
        int pos = atomicAdd(&cursor[dst[e]], 1);
        src_sorted[pos] = src[e];
    }
}

// ---------------------------------------------------------------------------
// Stage 4: h(bf16) = diag(rsqrt(max(deg_out,1))) * X * W via 16x16x32 bf16 MFMA.
// Block: 256 thr / 4 waves, 64 rows, full K=256 in LDS (one barrier).
// LDS: sx[64r][256k] bf16 @0, WT[64f][256k] bf16 @32768; both XOR-swizzled.
// Swizzle is applied to the k-byte-offset ONLY (bits 4-8 ^ bits 4-6), then
// added to the row base (bits >=9) -> provably carry-free, matching writes.
// ---------------------------------------------------------------------------
__global__ __launch_bounds__(256) void k_gemm(const float* __restrict__ x,
                                              const float* __restrict__ W,
                                              const int* __restrict__ deg_out,
                                              unsigned short* __restrict__ h, int n) {
    __shared__ char lds[65536];
    const int tid = threadIdx.x;
    const int lane = tid & 63;
    const int wid = tid >> 6;
    const int row0 = blockIdx.x * 64;

    // ---- stage W^T (bf16, swizzled): thread t covers f = t&63, k in [(t>>6)*64, +64)
    {
        const int f = tid & 63;
        const int kg = (tid >> 6) * 64;
        const int swz = (f & 7) << 4;
#pragma unroll
        for (int j = 0; j < 16; ++j) {
            const int k0 = kg + j * 4;
            unsigned u0 = bf16_rne(W[(k0 + 0) * OUT_F + f]);
            unsigned u1 = bf16_rne(W[(k0 + 1) * OUT_F + f]);
            unsigned u2 = bf16_rne(W[(k0 + 2) * OUT_F + f]);
            unsigned u3 = bf16_rne(W[(k0 + 3) * OUT_F + f]);
            uint2 p;
            p.x = u0 | (u1 << 16);
            p.y = u2 | (u3 << 16);
            int byte = 32768 + f * 512 + ((k0 * 2) ^ swz);
            *(uint2*)(lds + byte) = p;
        }
    }
    // ---- stage x tile (scaled, bf16, swizzled): 16 float4 per thread, coalesced
    {
#pragma unroll
        for (int i = 0; i < 16; ++i) {
            const int flat = tid + i * 256;
            const int r = flat >> 6;
            const int c4 = flat & 63;
            const int grow = row0 + r;
            float4 v = make_float4(0.f, 0.f, 0.f, 0.f);
            float s = 0.0f;
            if (grow < n) {
                v = *(const float4*)&x[(size_t)grow * IN_F + c4 * 4];
                s = rsqrtf(fmaxf((float)deg_out[grow], 1.0f));
            }
            uint2 p;
            p.x = (unsigned)bf16_rne(v.x * s) | ((unsigned)bf16_rne(v.y * s) << 16);
            p.y = (unsigned)bf16_rne(v.z * s) | ((unsigned)bf16_rne(v.w * s) << 16);
            int byte = r * 512 + ((c4 * 8) ^ ((r & 7) << 4));
            *(uint2*)(lds + byte) = p;
        }
    }
    __syncthreads();

    f32x4 acc0 = {0.f, 0.f, 0.f, 0.f};
    f32x4 acc1 = acc0, acc2 = acc0, acc3 = acc0;

    const int arow = lane & 15;          // A row in wave tile / B col within 16
    const int kq16 = (lane >> 4) * 16;   // 8 bf16 = 16 B k-subchunk per lane quarter
    const int swz = (arow & 7) << 4;
    const int a_base = (wid * 16 + arow) * 512;   // (wid*16+arow)&7 == arow&7
    const int b_base = 32768 + arow * 512;

#pragma unroll
    for (int kk = 0; kk < 8; ++kk) {
        const int off = (kq16 + kk * 64) ^ swz;   // bits 4-8 ^ bits 4-6: carry-free
        s16x8 a  = *(const s16x8*)(lds + a_base + off);
        s16x8 b0 = *(const s16x8*)(lds + b_base + off);
        s16x8 b1 = *(const s16x8*)(lds + b_base + 8192 + off);
        s16x8 b2 = *(const s16x8*)(lds + b_base + 16384 + off);
        s16x8 b3 = *(const s16x8*)(lds + b_base + 24576 + off);
        acc0 = __builtin_amdgcn_mfma_f32_16x16x32_bf16(a, b0, acc0, 0, 0, 0);
        acc1 = __builtin_amdgcn_mfma_f32_16x16x32_bf16(a, b1, acc1, 0, 0, 0);
        acc2 = __builtin_amdgcn_mfma_f32_16x16x32_bf16(a, b2, acc2, 0, 0, 0);
        acc3 = __builtin_amdgcn_mfma_f32_16x16x32_bf16(a, b3, acc3, 0, 0, 0);
    }

    // D layout: row=(lane>>4)*4+j, col=lane&15 (m89-verified)
    const int rq = (lane >> 4) * 4;
    const int col = lane & 15;
#pragma unroll
    for (int j = 0; j < 4; ++j) {
        const int grow = row0 + wid * 16 + rq + j;
        if (grow < n) {
            unsigned short* hp = h + (size_t)grow * OUT_F + col;
            hp[0]  = bf16_rne(acc0[j]);
            hp[16] = bf16_rne(acc1[j]);
            hp[32] = bf16_rne(acc2[j]);
            hp[48] = bf16_rne(acc3[j]);
        }
    }
}

// ---------------------------------------------------------------------------
// Stage 5: CSR gather-aggregate (bf16 h) + scale + bias. Wave/node, lane=feat.
// ---------------------------------------------------------------------------
__global__ __launch_bounds__(256) void k_aggregate(const int* __restrict__ row_ptr,
                                                   const int* __restrict__ deg_in,
                                                   const int* __restrict__ src_sorted,
                                                   const unsigned short* __restrict__ h,
                                                   const float* __restrict__ b,
                                                   float* __restrict__ out, int n) {
    const int node = __builtin_amdgcn_readfirstlane(blockIdx.x * 4 + (threadIdx.x >> 6));
    const int f = threadIdx.x & 63;
    if (node >= n) return;
    const int start = row_ptr[node];
    const int deg = deg_in[node];
    float a0 = 0.f, a1 = 0.f;
    int i = 0;
    for (; i + 2 <= deg; i += 2) {
        int s0 = src_sorted[start + i];
        int s1 = src_sorted[start + i + 1];
        a0 += bf16_f(h[(size_t)s0 * OUT_F + f]);
        a1 += bf16_f(h[(size_t)s1 * OUT_F + f]);
    }
    if (i < deg) a0 += bf16_f(h[(size_t)src_sorted[start + i] * OUT_F + f]);
    float scale = rsqrtf(fmaxf((float)deg, 1.0f));
    out[(size_t)node * OUT_F + f] = (a0 + a1) * scale + b[f];
}

extern "C" void kernel_launch(void* const* d_in, const int* in_sizes, int n_in,
                              void* d_out, int out_size, void* d_ws, size_t ws_size,
                              hipStream_t stream) {
    const float* x   = (const float*)d_in[0];
    const int*   src = (const int*)d_in[1];
    const int*   dst = (const int*)d_in[2];
    const float* W   = (const float*)d_in[3];
    const float* b   = (const float*)d_in[4];
    float* out = (float*)d_out;

    const int n  = in_sizes[0] / IN_F;   // 100000
    const int ne = in_sizes[1];          // 1000000

    int* deg_out_i  = (int*)d_ws;
    int* deg_in_i   = deg_out_i + n;
    int* cursor     = deg_in_i + n;
    int* row_ptr    = cursor + n;
    int* partials   = row_ptr + n;
    int* src_sorted = partials + 256;
    unsigned short* h = (unsigned short*)(src_sorted + ne + 8);

    const int nb_scan = (n + 1023) / 1024;  // 98 (<= 256)

    hipMemsetAsync(deg_out_i, 0, 2ull * n * sizeof(int), stream);

    k_hist<<<(ne + 255) / 256, 256, 0, stream>>>(src, dst, deg_out_i, deg_in_i, ne);
    k_scan1<<<nb_scan, 256, 0, stream>>>(deg_in_i, row_ptr, partials, n);
    k_scan2<<<1, 256, 0, stream>>>(partials, nb_scan);
    k_scan3<<<(n + 255) / 256, 256, 0, stream>>>(row_ptr, cursor, partials, n);
    k_scatter<<<(ne + 255) / 256, 256, 0, stream>>>(src, dst, cursor, src_sorted, ne);
    k_gemm<<<(n + 63) / 64, 256, 0, stream>>>(x, W, deg_out_i, h, n);
    k_aggregate<<<(n + 3) / 4, 256, 0, stream>>>(row_ptr, deg_in_i, src_sorted, h, b, out, n);
}

// Round 5
// 247.815 us; speedup vs baseline: 1.7553x; 1.0053x over previous
//
#include <hip/hip_runtime.h>

#define IN_F 256
#define OUT_F 64
#define NXCD 8

typedef __attribute__((ext_vector_type(8))) short s16x8;
typedef __attribute__((ext_vector_type(4))) float f32x4;

__device__ __forceinline__ unsigned short bf16_rne(float f) {
    unsigned u = __builtin_bit_cast(unsigned, f);
    u += 0x7FFFu + ((u >> 16) & 1u);
    return (unsigned short)(u >> 16);
}
__device__ __forceinline__ float bf16_f(unsigned short u) {
    unsigned v = ((unsigned)u) << 16;
    return __builtin_bit_cast(float, v);
}
__device__ __forceinline__ int xcc_id() {
    int xcc;
    asm volatile("s_getreg_b32 %0, hwreg(HW_REG_XCC_ID)" : "=s"(xcc));
    return xcc & (NXCD - 1);
}

// ---------------------------------------------------------------------------
// Stage 1: per-XCD partial degree histograms. Workgroup-scope atomics stay in
// the local XCD's L2 (no sc1 write-through) — each copy touched by one XCD only.
// ---------------------------------------------------------------------------
__global__ __launch_bounds__(256) void k_hist(const int* __restrict__ src,
                                              const int* __restrict__ dst,
                                              int* __restrict__ deg_out_p,
                                              int* __restrict__ deg_in_p,
                                              int n, int ne) {
    const int xcc = xcc_id();
    int e = blockIdx.x * 256 + threadIdx.x;
    if (e < ne) {
        __hip_atomic_fetch_add(&deg_out_p[(size_t)xcc * n + src[e]], 1,
                               __ATOMIC_RELAXED, __HIP_MEMORY_SCOPE_WORKGROUP);
        __hip_atomic_fetch_add(&deg_in_p[(size_t)xcc * n + dst[e]], 1,
                               __ATOMIC_RELAXED, __HIP_MEMORY_SCOPE_WORKGROUP);
    }
}

// ---------------------------------------------------------------------------
// Stage 1b: reduce 8 partials -> deg_out, deg_in totals.
// ---------------------------------------------------------------------------
__global__ __launch_bounds__(256) void k_reduce(const int* __restrict__ deg_out_p,
                                                const int* __restrict__ deg_in_p,
                                                int* __restrict__ deg_out,
                                                int* __restrict__ deg_in, int n) {
    int i = blockIdx.x * 256 + threadIdx.x;
    if (i < n) {
        int s0 = 0, s1 = 0;
#pragma unroll
        for (int c = 0; c < NXCD; ++c) {
            s0 += deg_out_p[(size_t)c * n + i];
            s1 += deg_in_p[(size_t)c * n + i];
        }
        deg_out[i] = s0;
        deg_in[i] = s1;
    }
}

// ---------------------------------------------------------------------------
// Stage 2: exclusive scan of deg_in -> row_ptr.
// ---------------------------------------------------------------------------
__global__ __launch_bounds__(256) void k_scan1(const int* __restrict__ deg,
                                               int* __restrict__ excl,
                                               int* __restrict__ partials, int n) {
    __shared__ int sd[256];
    const int tid = threadIdx.x;
    const int idx = blockIdx.x * 1024 + tid * 4;
    int v0 = 0, v1 = 0, v2 = 0, v3 = 0;
    if (idx     < n) v0 = deg[idx];
    if (idx + 1 < n) v1 = deg[idx + 1];
    if (idx + 2 < n) v2 = deg[idx + 2];
    if (idx + 3 < n) v3 = deg[idx + 3];
    const int tsum = v0 + v1 + v2 + v3;
    sd[tid] = tsum;
    __syncthreads();
    for (int off = 1; off < 256; off <<= 1) {
        int t = (tid >= off) ? sd[tid - off] : 0;
        __syncthreads();
        sd[tid] += t;
        __syncthreads();
    }
    const int texcl = sd[tid] - tsum;
    if (tid == 255) partials[blockIdx.x] = sd[255];
    if (idx     < n) excl[idx]     = texcl;
    if (idx + 1 < n) excl[idx + 1] = texcl + v0;
    if (idx + 2 < n) excl[idx + 2] = texcl + v0 + v1;
    if (idx + 3 < n) excl[idx + 3] = texcl + v0 + v1 + v2;
}

__global__ __launch_bounds__(256) void k_scan2(int* __restrict__ partials, int nb) {
    __shared__ int sd[256];
    const int tid = threadIdx.x;
    const int v = (tid < nb) ? partials[tid] : 0;
    sd[tid] = v;
    __syncthreads();
    for (int off = 1; off < 256; off <<= 1) {
        int t = (tid >= off) ? sd[tid - off] : 0;
        __syncthreads();
        sd[tid] += t;
        __syncthreads();
    }
    if (tid < nb) partials[tid] = sd[tid] - v;  // exclusive
}

// Stage 2b: finalize row_ptr AND seed per-(XCD,node) cursors in-place over
// deg_in_p (read partial count, write seed — element-wise safe).
__global__ __launch_bounds__(256) void k_scan3(int* __restrict__ excl,
                                               int* __restrict__ cursor2,
                                               const int* __restrict__ partials, int n) {
    int i = blockIdx.x * 256 + threadIdx.x;
    if (i < n) {
        int v = excl[i] + partials[blockIdx.x >> 2];
        excl[i] = v;
        int base = v;
#pragma unroll
        for (int c = 0; c < NXCD; ++c) {
            int d = cursor2[(size_t)c * n + i];
            cursor2[(size_t)c * n + i] = base;
            base += d;
        }
    }
}

// ---------------------------------------------------------------------------
// Stage 3: scatter edges into dst-sorted CSR order via per-XCD local-L2 cursors.
// Each node's range is contiguous, sub-ordered by XCD.
// ---------------------------------------------------------------------------
__global__ __launch_bounds__(256) void k_scatter(const int* __restrict__ src,
                                                 const int* __restrict__ dst,
                                                 int* __restrict__ cursor2,
                                                 int* __restrict__ src_sorted,
                                                 int n, int ne) {
    const int xcc = xcc_id();
    int e = blockIdx.x * 256 + threadIdx.x;
    if (e < ne) {
        int pos = __hip_atomic_fetch_add(&cursor2[(size_t)xcc * n + dst[e]], 1,
                                         __ATOMIC_RELAXED, __HIP_MEMORY_SCOPE_WORKGROUP);
        src_sorted[pos] = src[e];
    }
}

// ---------------------------------------------------------------------------
// Stage 4: h(bf16) = diag(rsqrt(max(deg_out,1))) * X * W via 16x16x32 bf16 MFMA.
// ---------------------------------------------------------------------------
__global__ __launch_bounds__(256) void k_gemm(const float* __restrict__ x,
                                              const float* __restrict__ W,
                                              const int* __restrict__ deg_out,
                                              unsigned short* __restrict__ h, int n) {
    __shared__ char lds[65536];
    const int tid = threadIdx.x;
    const int lane = tid & 63;
    const int wid = tid >> 6;
    const int row0 = blockIdx.x * 64;

    {
        const int f = tid & 63;
        const int kg = (tid >> 6) * 64;
        const int swz = (f & 7) << 4;
#pragma unroll
        for (int j = 0; j < 16; ++j) {
            const int k0 = kg + j * 4;
            unsigned u0 = bf16_rne(W[(k0 + 0) * OUT_F + f]);
            unsigned u1 = bf16_rne(W[(k0 + 1) * OUT_F + f]);
            unsigned u2 = bf16_rne(W[(k0 + 2) * OUT_F + f]);
            unsigned u3 = bf16_rne(W[(k0 + 3) * OUT_F + f]);
            uint2 p;
            p.x = u0 | (u1 << 16);
            p.y = u2 | (u3 << 16);
            int byte = 32768 + f * 512 + ((k0 * 2) ^ swz);
            *(uint2*)(lds + byte) = p;
        }
    }
    {
#pragma unroll
        for (int i = 0; i < 16; ++i) {
            const int flat = tid + i * 256;
            const int r = flat >> 6;
            const int c4 = flat & 63;
            const int grow = row0 + r;
            float4 v = make_float4(0.f, 0.f, 0.f, 0.f);
            float s = 0.0f;
            if (grow < n) {
                v = *(const float4*)&x[(size_t)grow * IN_F + c4 * 4];
                s = rsqrtf(fmaxf((float)deg_out[grow], 1.0f));
            }
            uint2 p;
            p.x = (unsigned)bf16_rne(v.x * s) | ((unsigned)bf16_rne(v.y * s) << 16);
            p.y = (unsigned)bf16_rne(v.z * s) | ((unsigned)bf16_rne(v.w * s) << 16);
            int byte = r * 512 + ((c4 * 8) ^ ((r & 7) << 4));
            *(uint2*)(lds + byte) = p;
        }
    }
    __syncthreads();

    f32x4 acc0 = {0.f, 0.f, 0.f, 0.f};
    f32x4 acc1 = acc0, acc2 = acc0, acc3 = acc0;

    const int arow = lane & 15;
    const int kq16 = (lane >> 4) * 16;
    const int swz = (arow & 7) << 4;
    const int a_base = (wid * 16 + arow) * 512;
    const int b_base = 32768 + arow * 512;

#pragma unroll
    for (int kk = 0; kk < 8; ++kk) {
        const int off = (kq16 + kk * 64) ^ swz;   // bits 4-8 ^ bits 4-6: carry-free
        s16x8 a  = *(const s16x8*)(lds + a_base + off);
        s16x8 b0 = *(const s16x8*)(lds + b_base + off);
        s16x8 b1 = *(const s16x8*)(lds + b_base + 8192 + off);
        s16x8 b2 = *(const s16x8*)(lds + b_base + 16384 + off);
        s16x8 b3 = *(const s16x8*)(lds + b_base + 24576 + off);
        acc0 = __builtin_amdgcn_mfma_f32_16x16x32_bf16(a, b0, acc0, 0, 0, 0);
        acc1 = __builtin_amdgcn_mfma_f32_16x16x32_bf16(a, b1, acc1, 0, 0, 0);
        acc2 = __builtin_amdgcn_mfma_f32_16x16x32_bf16(a, b2, acc2, 0, 0, 0);
        acc3 = __builtin_amdgcn_mfma_f32_16x16x32_bf16(a, b3, acc3, 0, 0, 0);
    }

    const int rq = (lane >> 4) * 4;
    const int col = lane & 15;
#pragma unroll
    for (int j = 0; j < 4; ++j) {
        const int grow = row0 + wid * 16 + rq + j;
        if (grow < n) {
            unsigned short* hp = h + (size_t)grow * OUT_F + col;
            hp[0]  = bf16_rne(acc0[j]);
            hp[16] = bf16_rne(acc1[j]);
            hp[32] = bf16_rne(acc2[j]);
            hp[48] = bf16_rne(acc3[j]);
        }
    }
}

// ---------------------------------------------------------------------------
// Stage 5: CSR gather-aggregate (bf16 h) + scale + bias. Wave/node, lane=feat.
// ---------------------------------------------------------------------------
__global__ __launch_bounds__(256) void k_aggregate(const int* __restrict__ row_ptr,
                                                   const int* __restrict__ deg_in,
                                                   const int* __restrict__ src_sorted,
                                                   const unsigned short* __restrict__ h,
                                                   const float* __restrict__ b,
                                                   float* __restrict__ out, int n) {
    const int node = __builtin_amdgcn_readfirstlane(blockIdx.x * 4 + (threadIdx.x >> 6));
    const int f = threadIdx.x & 63;
    if (node >= n) return;
    const int start = row_ptr[node];
    const int deg = deg_in[node];
    float a0 = 0.f, a1 = 0.f;
    int i = 0;
    for (; i + 2 <= deg; i += 2) {
        int s0 = src_sorted[start + i];
        int s1 = src_sorted[start + i + 1];
        a0 += bf16_f(h[(size_t)s0 * OUT_F + f]);
        a1 += bf16_f(h[(size_t)s1 * OUT_F + f]);
    }
    if (i < deg) a0 += bf16_f(h[(size_t)src_sorted[start + i] * OUT_F + f]);
    float scale = rsqrtf(fmaxf((float)deg, 1.0f));
    out[(size_t)node * OUT_F + f] = (a0 + a1) * scale + b[f];
}

extern "C" void kernel_launch(void* const* d_in, const int* in_sizes, int n_in,
                              void* d_out, int out_size, void* d_ws, size_t ws_size,
                              hipStream_t stream) {
    const float* x   = (const float*)d_in[0];
    const int*   src = (const int*)d_in[1];
    const int*   dst = (const int*)d_in[2];
    const float* W   = (const float*)d_in[3];
    const float* b   = (const float*)d_in[4];
    float* out = (float*)d_out;

    const int n  = in_sizes[0] / IN_F;   // 100000
    const int ne = in_sizes[1];          // 1000000

    int* deg_out_p  = (int*)d_ws;              // 8n
    int* deg_in_p   = deg_out_p + (size_t)NXCD * n;  // 8n (becomes cursor2)
    int* deg_out    = deg_in_p + (size_t)NXCD * n;   // n
    int* deg_in     = deg_out + n;             // n
    int* row_ptr    = deg_in + n;              // n
    int* partials   = row_ptr + n;             // 256
    int* src_sorted = partials + 256;          // ne
    unsigned short* h = (unsigned short*)(src_sorted + ne);  // n*64 bf16

    const int nb_scan = (n + 1023) / 1024;     // 98 (<= 256)

    // zero both partial-histogram arrays (contiguous 16n ints)
    hipMemsetAsync(deg_out_p, 0, (size_t)2 * NXCD * n * sizeof(int), stream);

    k_hist<<<(ne + 255) / 256, 256, 0, stream>>>(src, dst, deg_out_p, deg_in_p, n, ne);
    k_reduce<<<(n + 255) / 256, 256, 0, stream>>>(deg_out_p, deg_in_p, deg_out, deg_in, n);
    k_scan1<<<nb_scan, 256, 0, stream>>>(deg_in, row_ptr, partials, n);
    k_scan2<<<1, 256, 0, stream>>>(partials, nb_scan);
    k_scan3<<<(n + 255) / 256, 256, 0, stream>>>(row_ptr, deg_in_p, partials, n);
    k_scatter<<<(ne + 255) / 256, 256, 0, stream>>>(src, dst, deg_in_p, src_sorted, n, ne);
    k_gemm<<<(n + 63) / 64, 256, 0, stream>>>(x, W, deg_out, h, n);
    k_aggregate<<<(n + 3) / 4, 256, 0, stream>>>(row_ptr, deg_in, src_sorted, h, b, out, n);
}

// Round 6
// 141.208 us; speedup vs baseline: 3.0805x; 1.7550x over previous
//
#include <hip/hip_runtime.h>

#define IN_F 256
#define OUT_F 64
#define BLK1 512          // blocks in coarse passes (P1/P2)

typedef __attribute__((ext_vector_type(8))) short s16x8;
typedef __attribute__((ext_vector_type(4))) float f32x4;

__device__ __forceinline__ unsigned short bf16_rne(float f) {
    unsigned u = __builtin_bit_cast(unsigned, f);
    u += 0x7FFFu + ((u >> 16) & 1u);
    return (unsigned short)(u >> 16);
}
__device__ __forceinline__ float bf16_f(unsigned short u) {
    unsigned v = ((unsigned)u) << 16;
    return __builtin_bit_cast(float, v);
}

// ---------------------------------------------------------------------------
// P1: per-block coarse-bucket histograms (bucket = node>>8) for dst AND src,
// via LDS atomics. cnt layout (bucket-major): dst -> [b*BLK1+blk],
// src -> [(NB+b)*BLK1+blk]. No global atomics anywhere.
// ---------------------------------------------------------------------------
__global__ __launch_bounds__(256) void k_coarse(const int* __restrict__ src,
                                                const int* __restrict__ dst,
                                                int* __restrict__ cnt,
                                                int nb, int ne) {
    __shared__ int hD[512], hS[512];
    const int blk = blockIdx.x, tid = threadIdx.x;
    for (int i = tid; i < 512; i += 256) { hD[i] = 0; hS[i] = 0; }
    __syncthreads();
    const int epb = (ne + BLK1 - 1) / BLK1;
    const int e0 = blk * epb, e1 = min(ne, e0 + epb);
    for (int e = e0 + tid; e < e1; e += 256) {
        atomicAdd(&hD[dst[e] >> 8], 1);
        atomicAdd(&hS[src[e] >> 8], 1);
    }
    __syncthreads();
    for (int bb = tid; bb < nb; bb += 256) {
        cnt[bb * BLK1 + blk] = hD[bb];
        cnt[(nb + bb) * BLK1 + blk] = hS[bb];
    }
}

// ---------------------------------------------------------------------------
// Exclusive scan over m = 2*NB*BLK1 elements (3-kernel hierarchy, <=512 blocks).
// ---------------------------------------------------------------------------
__global__ __launch_bounds__(256) void k_scan1(const int* __restrict__ deg,
                                               int* __restrict__ excl,
                                               int* __restrict__ partials, int m) {
    __shared__ int sd[256];
    const int tid = threadIdx.x;
    const int idx = blockIdx.x * 1024 + tid * 4;
    int v0 = 0, v1 = 0, v2 = 0, v3 = 0;
    if (idx     < m) v0 = deg[idx];
    if (idx + 1 < m) v1 = deg[idx + 1];
    if (idx + 2 < m) v2 = deg[idx + 2];
    if (idx + 3 < m) v3 = deg[idx + 3];
    const int tsum = v0 + v1 + v2 + v3;
    sd[tid] = tsum;
    __syncthreads();
    for (int off = 1; off < 256; off <<= 1) {
        int t = (tid >= off) ? sd[tid - off] : 0;
        __syncthreads();
        sd[tid] += t;
        __syncthreads();
    }
    const int texcl = sd[tid] - tsum;
    if (tid == 255) partials[blockIdx.x] = sd[255];
    if (idx     < m) excl[idx]     = texcl;
    if (idx + 1 < m) excl[idx + 1] = texcl + v0;
    if (idx + 2 < m) excl[idx + 2] = texcl + v0 + v1;
    if (idx + 3 < m) excl[idx + 3] = texcl + v0 + v1 + v2;
}

__global__ __launch_bounds__(512) void k_scan2(int* __restrict__ partials, int nb) {
    __shared__ int sd[512];
    const int tid = threadIdx.x;
    const int v = (tid < nb) ? partials[tid] : 0;
    sd[tid] = v;
    __syncthreads();
    for (int off = 1; off < 512; off <<= 1) {
        int t = (tid >= off) ? sd[tid - off] : 0;
        __syncthreads();
        sd[tid] += t;
        __syncthreads();
    }
    if (tid < nb) partials[tid] = sd[tid] - v;  // exclusive
}

__global__ __launch_bounds__(256) void k_scan3(int* __restrict__ excl,
                                               const int* __restrict__ partials, int m) {
    int i = blockIdx.x * 256 + threadIdx.x;
    if (i < m) excl[i] += partials[blockIdx.x >> 2];
}

// ---------------------------------------------------------------------------
// P2: partition edges into coarse buckets via LDS cursors (scanned offsets).
// dst entry: (dst&255)<<17 | src (25 bits); src entry: src&255.
// dst entries land in tmp[0,ne), src entries in tmp[ne,2ne) by construction.
// ---------------------------------------------------------------------------
__global__ __launch_bounds__(256) void k_part(const int* __restrict__ src,
                                              const int* __restrict__ dst,
                                              const int* __restrict__ cnt,
                                              unsigned* __restrict__ tmp,
                                              int nb, int ne) {
    __shared__ int cD[512], cS[512];
    const int blk = blockIdx.x, tid = threadIdx.x;
    for (int bb = tid; bb < nb; bb += 256) {
        cD[bb] = cnt[bb * BLK1 + blk];
        cS[bb] = cnt[(nb + bb) * BLK1 + blk];
    }
    __syncthreads();
    const int epb = (ne + BLK1 - 1) / BLK1;
    const int e0 = blk * epb, e1 = min(ne, e0 + epb);
    for (int e = e0 + tid; e < e1; e += 256) {
        int d = dst[e], s = src[e];
        int pD = atomicAdd(&cD[d >> 8], 1);
        tmp[pD] = ((unsigned)(d & 255) << 17) | (unsigned)s;
        int pS = atomicAdd(&cS[s >> 8], 1);
        tmp[pS] = (unsigned)(s & 255);
    }
}

// ---------------------------------------------------------------------------
// P3-dst: one block per bucket. LDS 256-bin histogram -> deg_in + row_ptr
// (bucket base + LDS exclusive scan), then LDS-cursor scatter -> src_sorted.
// ---------------------------------------------------------------------------
__global__ __launch_bounds__(256) void k_fine_dst(const int* __restrict__ cnt,
                                                  const unsigned* __restrict__ tmp,
                                                  int* __restrict__ src_sorted,
                                                  int* __restrict__ deg_in,
                                                  int* __restrict__ row_ptr,
                                                  int n, int nb, int ne) {
    __shared__ int hist[256], sd[256], cur[256];
    const int b = blockIdx.x, tid = threadIdx.x;
    const int base = cnt[b * BLK1];
    const int end = (b + 1 < nb) ? cnt[(b + 1) * BLK1] : ne;
    hist[tid] = 0;
    __syncthreads();
    for (int i = base + tid; i < end; i += 256)
        atomicAdd(&hist[tmp[i] >> 17], 1);
    __syncthreads();
    const int deg = hist[tid];
    sd[tid] = deg;
    __syncthreads();
    for (int off = 1; off < 256; off <<= 1) {
        int t = (tid >= off) ? sd[tid - off] : 0;
        __syncthreads();
        sd[tid] += t;
        __syncthreads();
    }
    const int excl = sd[tid] - deg;
    cur[tid] = excl;
    const int node = b * 256 + tid;
    if (node < n) { deg_in[node] = deg; row_ptr[node] = base + excl; }
    __syncthreads();
    for (int i = base + tid; i < end; i += 256) {
        unsigned v = tmp[i];
        int pos = base + atomicAdd(&cur[v >> 17], 1);
        src_sorted[pos] = (int)(v & 0x1FFFFu);
    }
}

// ---------------------------------------------------------------------------
// P3-src: one block per bucket. LDS histogram of src entries -> deg_out.
// ---------------------------------------------------------------------------
__global__ __launch_bounds__(256) void k_fine_src(const int* __restrict__ cnt,
                                                  const unsigned* __restrict__ tmp,
                                                  int* __restrict__ deg_out,
                                                  int n, int nb, int ne) {
    __shared__ int hist[256];
    const int b = blockIdx.x, tid = threadIdx.x;
    const int base = cnt[(nb + b) * BLK1];
    const int end = (b + 1 < nb) ? cnt[(nb + b + 1) * BLK1] : 2 * ne;
    hist[tid] = 0;
    __syncthreads();
    for (int i = base + tid; i < end; i += 256)
        atomicAdd(&hist[tmp[i] & 255u], 1);
    __syncthreads();
    const int node = b * 256 + tid;
    if (node < n) deg_out[node] = hist[tid];
}

// ---------------------------------------------------------------------------
// GEMM: h(bf16) = diag(rsqrt(max(deg_out,1))) * X * W via 16x16x32 bf16 MFMA.
// ---------------------------------------------------------------------------
__global__ __launch_bounds__(256) void k_gemm(const float* __restrict__ x,
                                              const float* __restrict__ W,
                                              const int* __restrict__ deg_out,
                                              unsigned short* __restrict__ h, int n) {
    __shared__ char lds[65536];
    const int tid = threadIdx.x;
    const int lane = tid & 63;
    const int wid = tid >> 6;
    const int row0 = blockIdx.x * 64;

    {
        const int f = tid & 63;
        const int kg = (tid >> 6) * 64;
        const int swz = (f & 7) << 4;
#pragma unroll
        for (int j = 0; j < 16; ++j) {
            const int k0 = kg + j * 4;
            unsigned u0 = bf16_rne(W[(k0 + 0) * OUT_F + f]);
            unsigned u1 = bf16_rne(W[(k0 + 1) * OUT_F + f]);
            unsigned u2 = bf16_rne(W[(k0 + 2) * OUT_F + f]);
            unsigned u3 = bf16_rne(W[(k0 + 3) * OUT_F + f]);
            uint2 p;
            p.x = u0 | (u1 << 16);
            p.y = u2 | (u3 << 16);
            int byte = 32768 + f * 512 + ((k0 * 2) ^ swz);
            *(uint2*)(lds + byte) = p;
        }
    }
    {
#pragma unroll
        for (int i = 0; i < 16; ++i) {
            const int flat = tid + i * 256;
            const int r = flat >> 6;
            const int c4 = flat & 63;
            const int grow = row0 + r;
            float4 v = make_float4(0.f, 0.f, 0.f, 0.f);
            float s = 0.0f;
            if (grow < n) {
                v = *(const float4*)&x[(size_t)grow * IN_F + c4 * 4];
                s = rsqrtf(fmaxf((float)deg_out[grow], 1.0f));
            }
            uint2 p;
            p.x = (unsigned)bf16_rne(v.x * s) | ((unsigned)bf16_rne(v.y * s) << 16);
            p.y = (unsigned)bf16_rne(v.z * s) | ((unsigned)bf16_rne(v.w * s) << 16);
            int byte = r * 512 + ((c4 * 8) ^ ((r & 7) << 4));
            *(uint2*)(lds + byte) = p;
        }
    }
    __syncthreads();

    f32x4 acc0 = {0.f, 0.f, 0.f, 0.f};
    f32x4 acc1 = acc0, acc2 = acc0, acc3 = acc0;

    const int arow = lane & 15;
    const int kq16 = (lane >> 4) * 16;
    const int swz = (arow & 7) << 4;
    const int a_base = (wid * 16 + arow) * 512;
    const int b_base = 32768 + arow * 512;

#pragma unroll
    for (int kk = 0; kk < 8; ++kk) {
        const int off = (kq16 + kk * 64) ^ swz;   // bits 4-8 ^ bits 4-6: carry-free
        s16x8 a  = *(const s16x8*)(lds + a_base + off);
        s16x8 b0 = *(const s16x8*)(lds + b_base + off);
        s16x8 b1 = *(const s16x8*)(lds + b_base + 8192 + off);
        s16x8 b2 = *(const s16x8*)(lds + b_base + 16384 + off);
        s16x8 b3 = *(const s16x8*)(lds + b_base + 24576 + off);
        acc0 = __builtin_amdgcn_mfma_f32_16x16x32_bf16(a, b0, acc0, 0, 0, 0);
        acc1 = __builtin_amdgcn_mfma_f32_16x16x32_bf16(a, b1, acc1, 0, 0, 0);
        acc2 = __builtin_amdgcn_mfma_f32_16x16x32_bf16(a, b2, acc2, 0, 0, 0);
        acc3 = __builtin_amdgcn_mfma_f32_16x16x32_bf16(a, b3, acc3, 0, 0, 0);
    }

    const int rq = (lane >> 4) * 4;
    const int col = lane & 15;
#pragma unroll
    for (int j = 0; j < 4; ++j) {
        const int grow = row0 + wid * 16 + rq + j;
        if (grow < n) {
            unsigned short* hp = h + (size_t)grow * OUT_F + col;
            hp[0]  = bf16_rne(acc0[j]);
            hp[16] = bf16_rne(acc1[j]);
            hp[32] = bf16_rne(acc2[j]);
            hp[48] = bf16_rne(acc3[j]);
        }
    }
}

// ---------------------------------------------------------------------------
// CSR gather-aggregate (bf16 h) + scale + bias. Wave/node, lane=feat.
// ---------------------------------------------------------------------------
__global__ __launch_bounds__(256) void k_aggregate(const int* __restrict__ row_ptr,
                                                   const int* __restrict__ deg_in,
                                                   const int* __restrict__ src_sorted,
                                                   const unsigned short* __restrict__ h,
                                                   const float* __restrict__ b,
                                                   float* __restrict__ out, int n) {
    const int node = __builtin_amdgcn_readfirstlane(blockIdx.x * 4 + (threadIdx.x >> 6));
    const int f = threadIdx.x & 63;
    if (node >= n) return;
    const int start = row_ptr[node];
    const int deg = deg_in[node];
    float a0 = 0.f, a1 = 0.f;
    int i = 0;
    for (; i + 2 <= deg; i += 2) {
        int s0 = src_sorted[start + i];
        int s1 = src_sorted[start + i + 1];
        a0 += bf16_f(h[(size_t)s0 * OUT_F + f]);
        a1 += bf16_f(h[(size_t)s1 * OUT_F + f]);
    }
    if (i < deg) a0 += bf16_f(h[(size_t)src_sorted[start + i] * OUT_F + f]);
    float scale = rsqrtf(fmaxf((float)deg, 1.0f));
    out[(size_t)node * OUT_F + f] = (a0 + a1) * scale + b[f];
}

extern "C" void kernel_launch(void* const* d_in, const int* in_sizes, int n_in,
                              void* d_out, int out_size, void* d_ws, size_t ws_size,
                              hipStream_t stream) {
    const float* x   = (const float*)d_in[0];
    const int*   src = (const int*)d_in[1];
    const int*   dst = (const int*)d_in[2];
    const float* W   = (const float*)d_in[3];
    const float* b   = (const float*)d_in[4];
    float* out = (float*)d_out;

    const int n  = in_sizes[0] / IN_F;   // 100000
    const int ne = in_sizes[1];          // 1000000

    const int nb = (n + 255) >> 8;       // 391 coarse buckets (<= 512)
    const int m  = 2 * nb * BLK1;        // cnt matrix size (400384)

    int* cnt        = (int*)d_ws;                 // m
    int* partials   = cnt + m;                    // 512
    unsigned* tmp   = (unsigned*)(partials + 512);// 2*ne
    int* src_sorted = (int*)(tmp + 2 * (size_t)ne); // ne
    int* deg_in     = src_sorted + ne;            // n
    int* deg_out    = deg_in + n;                 // n
    int* row_ptr    = deg_out + n;                // n
    unsigned short* h = (unsigned short*)(row_ptr + n);  // n*64 bf16

    const int nb_scan = (m + 1023) / 1024;        // 391 (<= 512)

    k_coarse<<<BLK1, 256, 0, stream>>>(src, dst, cnt, nb, ne);
    k_scan1<<<nb_scan, 256, 0, stream>>>(cnt, cnt, partials, m);
    k_scan2<<<1, 512, 0, stream>>>(partials, nb_scan);
    k_scan3<<<(m + 255) / 256, 256, 0, stream>>>(cnt, partials, m);
    k_part<<<BLK1, 256, 0, stream>>>(src, dst, cnt, tmp, nb, ne);
    k_fine_dst<<<nb, 256, 0, stream>>>(cnt, tmp, src_sorted, deg_in, row_ptr, n, nb, ne);
    k_fine_src<<<nb, 256, 0, stream>>>(cnt, tmp, deg_out, n, nb, ne);
    k_gemm<<<(n + 63) / 64, 256, 0, stream>>>(x, W, deg_out, h, n);
    k_aggregate<<<(n + 3) / 4, 256, 0, stream>>>(row_ptr, deg_in, src_sorted, h, b, out, n);
}

// Round 7
// 129.425 us; speedup vs baseline: 3.3610x; 1.0910x over previous
//
#include <hip/hip_runtime.h>

#define IN_F 256
#define OUT_F 64
#define BLK1 512          // blocks in coarse passes (P1/P2)

typedef __attribute__((ext_vector_type(8))) short s16x8;
typedef __attribute__((ext_vector_type(4))) float f32x4;

__device__ __forceinline__ unsigned short bf16_rne(float f) {
    unsigned u = __builtin_bit_cast(unsigned, f);
    u += 0x7FFFu + ((u >> 16) & 1u);
    return (unsigned short)(u >> 16);
}
__device__ __forceinline__ float bf16_f(unsigned short u) {
    unsigned v = ((unsigned)u) << 16;
    return __builtin_bit_cast(float, v);
}

// ---------------------------------------------------------------------------
// P1: per-block coarse-bucket histograms (bucket = node>>8) for dst AND src,
// via LDS atomics. cnt layout (bucket-major): dst -> [b*BLK1+blk],
// src -> [(NB+b)*BLK1+blk]. No global atomics anywhere.
// ---------------------------------------------------------------------------
__global__ __launch_bounds__(256) void k_coarse(const int* __restrict__ src,
                                                const int* __restrict__ dst,
                                                int* __restrict__ cnt,
                                                int nb, int ne) {
    __shared__ int hD[512], hS[512];
    const int blk = blockIdx.x, tid = threadIdx.x;
    for (int i = tid; i < 512; i += 256) { hD[i] = 0; hS[i] = 0; }
    __syncthreads();
    const int epb = (ne + BLK1 - 1) / BLK1;
    const int e0 = blk * epb, e1 = min(ne, e0 + epb);
    for (int e = e0 + tid; e < e1; e += 256) {
        atomicAdd(&hD[dst[e] >> 8], 1);
        atomicAdd(&hS[src[e] >> 8], 1);
    }
    __syncthreads();
    for (int bb = tid; bb < nb; bb += 256) {
        cnt[bb * BLK1 + blk] = hD[bb];
        cnt[(nb + bb) * BLK1 + blk] = hS[bb];
    }
}

// ---------------------------------------------------------------------------
// Exclusive scan over m = 2*NB*BLK1 elements (3-kernel hierarchy, <=512 blocks).
// ---------------------------------------------------------------------------
__global__ __launch_bounds__(256) void k_scan1(const int* __restrict__ deg,
                                               int* __restrict__ excl,
                                               int* __restrict__ partials, int m) {
    __shared__ int sd[256];
    const int tid = threadIdx.x;
    const int idx = blockIdx.x * 1024 + tid * 4;
    int v0 = 0, v1 = 0, v2 = 0, v3 = 0;
    if (idx     < m) v0 = deg[idx];
    if (idx + 1 < m) v1 = deg[idx + 1];
    if (idx + 2 < m) v2 = deg[idx + 2];
    if (idx + 3 < m) v3 = deg[idx + 3];
    const int tsum = v0 + v1 + v2 + v3;
    sd[tid] = tsum;
    __syncthreads();
    for (int off = 1; off < 256; off <<= 1) {
        int t = (tid >= off) ? sd[tid - off] : 0;
        __syncthreads();
        sd[tid] += t;
        __syncthreads();
    }
    const int texcl = sd[tid] - tsum;
    if (tid == 255) partials[blockIdx.x] = sd[255];
    if (idx     < m) excl[idx]     = texcl;
    if (idx + 1 < m) excl[idx + 1] = texcl + v0;
    if (idx + 2 < m) excl[idx + 2] = texcl + v0 + v1;
    if (idx + 3 < m) excl[idx + 3] = texcl + v0 + v1 + v2;
}

__global__ __launch_bounds__(512) void k_scan2(int* __restrict__ partials, int nb) {
    __shared__ int sd[512];
    const int tid = threadIdx.x;
    const int v = (tid < nb) ? partials[tid] : 0;
    sd[tid] = v;
    __syncthreads();
    for (int off = 1; off < 512; off <<= 1) {
        int t = (tid >= off) ? sd[tid - off] : 0;
        __syncthreads();
        sd[tid] += t;
        __syncthreads();
    }
    if (tid < nb) partials[tid] = sd[tid] - v;  // exclusive
}

__global__ __launch_bounds__(256) void k_scan3(int* __restrict__ excl,
                                               const int* __restrict__ partials, int m) {
    int i = blockIdx.x * 256 + threadIdx.x;
    if (i < m) excl[i] += partials[blockIdx.x >> 2];
}

// ---------------------------------------------------------------------------
// P2: partition edges into coarse buckets via LDS cursors (scanned offsets).
// dst entry: (dst&255)<<17 | src (25 bits); src entry: src&255.
// dst entries land in tmp[0,ne), src entries in tmp[ne,2ne) by construction.
// ---------------------------------------------------------------------------
__global__ __launch_bounds__(256) void k_part(const int* __restrict__ src,
                                              const int* __restrict__ dst,
                                              const int* __restrict__ cnt,
                                              unsigned* __restrict__ tmp,
                                              int nb, int ne) {
    __shared__ int cD[512], cS[512];
    const int blk = blockIdx.x, tid = threadIdx.x;
    for (int bb = tid; bb < nb; bb += 256) {
        cD[bb] = cnt[bb * BLK1 + blk];
        cS[bb] = cnt[(nb + bb) * BLK1 + blk];
    }
    __syncthreads();
    const int epb = (ne + BLK1 - 1) / BLK1;
    const int e0 = blk * epb, e1 = min(ne, e0 + epb);
    for (int e = e0 + tid; e < e1; e += 256) {
        int d = dst[e], s = src[e];
        int pD = atomicAdd(&cD[d >> 8], 1);
        tmp[pD] = ((unsigned)(d & 255) << 17) | (unsigned)s;
        int pS = atomicAdd(&cS[s >> 8], 1);
        tmp[pS] = (unsigned)(s & 255);
    }
}

// ---------------------------------------------------------------------------
// P3-dst: one block per bucket. LDS 256-bin histogram -> deg_in + row_ptr
// (bucket base + LDS exclusive scan), then LDS-cursor scatter -> src_sorted.
// ---------------------------------------------------------------------------
__global__ __launch_bounds__(256) void k_fine_dst(const int* __restrict__ cnt,
                                                  const unsigned* __restrict__ tmp,
                                                  int* __restrict__ src_sorted,
                                                  int* __restrict__ deg_in,
                                                  int* __restrict__ row_ptr,
                                                  int n, int nb, int ne) {
    __shared__ int hist[256], sd[256], cur[256];
    const int b = blockIdx.x, tid = threadIdx.x;
    const int base = cnt[b * BLK1];
    const int end = (b + 1 < nb) ? cnt[(b + 1) * BLK1] : ne;
    hist[tid] = 0;
    __syncthreads();
    for (int i = base + tid; i < end; i += 256)
        atomicAdd(&hist[tmp[i] >> 17], 1);
    __syncthreads();
    const int deg = hist[tid];
    sd[tid] = deg;
    __syncthreads();
    for (int off = 1; off < 256; off <<= 1) {
        int t = (tid >= off) ? sd[tid - off] : 0;
        __syncthreads();
        sd[tid] += t;
        __syncthreads();
    }
    const int excl = sd[tid] - deg;
    cur[tid] = excl;
    const int node = b * 256 + tid;
    if (node < n) { deg_in[node] = deg; row_ptr[node] = base + excl; }
    __syncthreads();
    for (int i = base + tid; i < end; i += 256) {
        unsigned v = tmp[i];
        int pos = base + atomicAdd(&cur[v >> 17], 1);
        src_sorted[pos] = (int)(v & 0x1FFFFu);
    }
}

// ---------------------------------------------------------------------------
// P3-src: one block per bucket. LDS histogram of src entries -> deg_out.
// ---------------------------------------------------------------------------
__global__ __launch_bounds__(256) void k_fine_src(const int* __restrict__ cnt,
                                                  const unsigned* __restrict__ tmp,
                                                  int* __restrict__ deg_out,
                                                  int n, int nb, int ne) {
    __shared__ int hist[256];
    const int b = blockIdx.x, tid = threadIdx.x;
    const int base = cnt[(nb + b) * BLK1];
    const int end = (b + 1 < nb) ? cnt[(nb + b + 1) * BLK1] : 2 * ne;
    hist[tid] = 0;
    __syncthreads();
    for (int i = base + tid; i < end; i += 256)
        atomicAdd(&hist[tmp[i] & 255u], 1);
    __syncthreads();
    const int node = b * 256 + tid;
    if (node < n) deg_out[node] = hist[tid];
}

// ---------------------------------------------------------------------------
// GEMM v2: h(bf16) = diag(rsqrt(max(deg_out,1))) * X * W, 16x16x32 bf16 MFMA.
// A-fragments straight from global (coalesced: 4 k-quarters x 16 rows tile
// 16 full 128B lines per dwordx4), converted+scaled in-register. Only W^T
// (32 KB bf16, XOR-swizzled) in LDS, staged once per block, amortized over
// 2 row-tiles of 64 rows. No barrier in the main loop.
// ---------------------------------------------------------------------------
__global__ __launch_bounds__(256, 4) void k_gemm(const float* __restrict__ x,
                                                 const float* __restrict__ W,
                                                 const int* __restrict__ deg_out,
                                                 unsigned short* __restrict__ h, int n) {
    __shared__ char lds[32768];
    const int tid = threadIdx.x;
    const int lane = tid & 63;
    const int wid = tid >> 6;

    // ---- stage W^T (bf16, swizzled): thread t covers f = t&63, k in [(t>>6)*64, +64)
    {
        const int f = tid & 63;
        const int kg = (tid >> 6) * 64;
        const int swz = (f & 7) << 4;
#pragma unroll
        for (int j = 0; j < 16; ++j) {
            const int k0 = kg + j * 4;
            unsigned u0 = bf16_rne(W[(k0 + 0) * OUT_F + f]);
            unsigned u1 = bf16_rne(W[(k0 + 1) * OUT_F + f]);
            unsigned u2 = bf16_rne(W[(k0 + 2) * OUT_F + f]);
            unsigned u3 = bf16_rne(W[(k0 + 3) * OUT_F + f]);
            uint2 p;
            p.x = u0 | (u1 << 16);
            p.y = u2 | (u3 << 16);
            int byte = f * 512 + ((k0 * 2) ^ swz);
            *(uint2*)(lds + byte) = p;
        }
    }
    __syncthreads();

    const int r15 = lane & 15;           // A row within 16 / B col within 16
    const int q = lane >> 4;             // k-quarter
    const int bswz = (r15 & 7) << 4;
    const int b_base = r15 * 512;
    const int rq = q * 4;

#pragma unroll
    for (int p = 0; p < 2; ++p) {
        const int row = blockIdx.x * 128 + p * 64 + wid * 16 + r15;
        const int rowc = min(row, n - 1);                  // clamp (stores guarded)
        const float s = rsqrtf(fmaxf((float)deg_out[rowc], 1.0f));
        const float* xr = x + (size_t)rowc * IN_F + q * 8;

        f32x4 acc0 = {0.f, 0.f, 0.f, 0.f};
        f32x4 acc1 = acc0, acc2 = acc0, acc3 = acc0;

#pragma unroll
        for (int kk = 0; kk < 8; ++kk) {
            float4 a0 = *(const float4*)(xr + kk * 32);
            float4 a1 = *(const float4*)(xr + kk * 32 + 4);
            s16x8 a;
            a[0] = (short)bf16_rne(a0.x * s);
            a[1] = (short)bf16_rne(a0.y * s);
            a[2] = (short)bf16_rne(a0.z * s);
            a[3] = (short)bf16_rne(a0.w * s);
            a[4] = (short)bf16_rne(a1.x * s);
            a[5] = (short)bf16_rne(a1.y * s);
            a[6] = (short)bf16_rne(a1.z * s);
            a[7] = (short)bf16_rne(a1.w * s);
            const int off = (q * 16 + kk * 64) ^ bswz;     // XOR in bits 4-6: carry-free
            s16x8 b0 = *(const s16x8*)(lds + b_base + off);
            s16x8 b1 = *(const s16x8*)(lds + b_base + 8192 + off);
            s16x8 b2 = *(const s16x8*)(lds + b_base + 16384 + off);
            s16x8 b3 = *(const s16x8*)(lds + b_base + 24576 + off);
            acc0 = __builtin_amdgcn_mfma_f32_16x16x32_bf16(a, b0, acc0, 0, 0, 0);
            acc1 = __builtin_amdgcn_mfma_f32_16x16x32_bf16(a, b1, acc1, 0, 0, 0);
            acc2 = __builtin_amdgcn_mfma_f32_16x16x32_bf16(a, b2, acc2, 0, 0, 0);
            acc3 = __builtin_amdgcn_mfma_f32_16x16x32_bf16(a, b3, acc3, 0, 0, 0);
        }

        // D layout: row=(lane>>4)*4+j, col=lane&15 (m89-verified)
#pragma unroll
        for (int j = 0; j < 4; ++j) {
            const int grow = blockIdx.x * 128 + p * 64 + wid * 16 + rq + j;
            if (grow < n) {
                unsigned short* hp = h + (size_t)grow * OUT_F + r15;
                hp[0]  = bf16_rne(acc0[j]);
                hp[16] = bf16_rne(acc1[j]);
                hp[32] = bf16_rne(acc2[j]);
                hp[48] = bf16_rne(acc3[j]);
            }
        }
    }
}

// ---------------------------------------------------------------------------
// CSR gather-aggregate (bf16 h) + scale + bias. Wave/node, lane=feat.
// ---------------------------------------------------------------------------
__global__ __launch_bounds__(256) void k_aggregate(const int* __restrict__ row_ptr,
                                                   const int* __restrict__ deg_in,
                                                   const int* __restrict__ src_sorted,
                                                   const unsigned short* __restrict__ h,
                                                   const float* __restrict__ b,
                                                   float* __restrict__ out, int n) {
    const int node = __builtin_amdgcn_readfirstlane(blockIdx.x * 4 + (threadIdx.x >> 6));
    const int f = threadIdx.x & 63;
    if (node >= n) return;
    const int start = row_ptr[node];
    const int deg = deg_in[node];
    float a0 = 0.f, a1 = 0.f;
    int i = 0;
    for (; i + 2 <= deg; i += 2) {
        int s0 = src_sorted[start + i];
        int s1 = src_sorted[start + i + 1];
        a0 += bf16_f(h[(size_t)s0 * OUT_F + f]);
        a1 += bf16_f(h[(size_t)s1 * OUT_F + f]);
    }
    if (i < deg) a0 += bf16_f(h[(size_t)src_sorted[start + i] * OUT_F + f]);
    float scale = rsqrtf(fmaxf((float)deg, 1.0f));
    out[(size_t)node * OUT_F + f] = (a0 + a1) * scale + b[f];
}

extern "C" void kernel_launch(void* const* d_in, const int* in_sizes, int n_in,
                              void* d_out, int out_size, void* d_ws, size_t ws_size,
                              hipStream_t stream) {
    const float* x   = (const float*)d_in[0];
    const int*   src = (const int*)d_in[1];
    const int*   dst = (const int*)d_in[2];
    const float* W   = (const float*)d_in[3];
    const float* b   = (const float*)d_in[4];
    float* out = (float*)d_out;

    const int n  = in_sizes[0] / IN_F;   // 100000
    const int ne = in_sizes[1];          // 1000000

    const int nb = (n + 255) >> 8;       // 391 coarse buckets (<= 512)
    const int m  = 2 * nb * BLK1;        // cnt matrix size (400384)

    int* cnt        = (int*)d_ws;                 // m
    int* partials   = cnt + m;                    // 512
    unsigned* tmp   = (unsigned*)(partials + 512);// 2*ne
    int* src_sorted = (int*)(tmp + 2 * (size_t)ne); // ne
    int* deg_in     = src_sorted + ne;            // n
    int* deg_out    = deg_in + n;                 // n
    int* row_ptr    = deg_out + n;                // n
    unsigned short* h = (unsigned short*)(row_ptr + n);  // n*64 bf16

    const int nb_scan = (m + 1023) / 1024;        // 391 (<= 512)

    k_coarse<<<BLK1, 256, 0, stream>>>(src, dst, cnt, nb, ne);
    k_scan1<<<nb_scan, 256, 0, stream>>>(cnt, cnt, partials, m);
    k_scan2<<<1, 512, 0, stream>>>(partials, nb_scan);
    k_scan3<<<(m + 255) / 256, 256, 0, stream>>>(cnt, partials, m);
    k_part<<<BLK1, 256, 0, stream>>>(src, dst, cnt, tmp, nb, ne);
    k_fine_dst<<<nb, 256, 0, stream>>>(cnt, tmp, src_sorted, deg_in, row_ptr, n, nb, ne);
    k_fine_src<<<nb, 256, 0, stream>>>(cnt, tmp, deg_out, n, nb, ne);
    k_gemm<<<(n + 127) / 128, 256, 0, stream>>>(x, W, deg_out, h, n);
    k_aggregate<<<(n + 3) / 4, 256, 0, stream>>>(row_ptr, deg_in, src_sorted, h, b, out, n);
}

// Round 8
// 127.278 us; speedup vs baseline: 3.4177x; 1.0169x over previous
//
#include <hip/hip_runtime.h>

#define IN_F 256
#define OUT_F 64
#define BLK1 512          // blocks in coarse passes (P1/P2)

typedef __attribute__((ext_vector_type(8))) short s16x8;
typedef __attribute__((ext_vector_type(4))) float f32x4;

__device__ __forceinline__ unsigned short bf16_rne(float f) {
    unsigned u = __builtin_bit_cast(unsigned, f);
    u += 0x7FFFu + ((u >> 16) & 1u);
    return (unsigned short)(u >> 16);
}
__device__ __forceinline__ float bf16_lo(unsigned u) {
    return __builtin_bit_cast(float, u << 16);
}
__device__ __forceinline__ float bf16_hi(unsigned u) {
    return __builtin_bit_cast(float, u & 0xFFFF0000u);
}

// ---------------------------------------------------------------------------
// P1: per-block coarse-bucket histograms (bucket = node>>8) for dst AND src,
// via LDS atomics. cnt layout (bucket-major): dst -> [b*BLK1+blk],
// src -> [(NB+b)*BLK1+blk]. No global atomics anywhere.
// ---------------------------------------------------------------------------
__global__ __launch_bounds__(256) void k_coarse(const int* __restrict__ src,
                                                const int* __restrict__ dst,
                                                int* __restrict__ cnt,
                                                int nb, int ne) {
    __shared__ int hD[512], hS[512];
    const int blk = blockIdx.x, tid = threadIdx.x;
    for (int i = tid; i < 512; i += 256) { hD[i] = 0; hS[i] = 0; }
    __syncthreads();
    const int epb = (ne + BLK1 - 1) / BLK1;
    const int e0 = blk * epb, e1 = min(ne, e0 + epb);
    for (int e = e0 + tid; e < e1; e += 256) {
        atomicAdd(&hD[dst[e] >> 8], 1);
        atomicAdd(&hS[src[e] >> 8], 1);
    }
    __syncthreads();
    for (int bb = tid; bb < nb; bb += 256) {
        cnt[bb * BLK1 + blk] = hD[bb];
        cnt[(nb + bb) * BLK1 + blk] = hS[bb];
    }
}

// ---------------------------------------------------------------------------
// Exclusive scan over m = 2*NB*BLK1 elements. Two kernels; the final
// per-element partial add is folded into the consumers (k_part / k_fine_*).
// ---------------------------------------------------------------------------
__global__ __launch_bounds__(256) void k_scan1(const int* __restrict__ deg,
                                               int* __restrict__ excl,
                                               int* __restrict__ partials, int m) {
    __shared__ int sd[256];
    const int tid = threadIdx.x;
    const int idx = blockIdx.x * 1024 + tid * 4;
    int v0 = 0, v1 = 0, v2 = 0, v3 = 0;
    if (idx     < m) v0 = deg[idx];
    if (idx + 1 < m) v1 = deg[idx + 1];
    if (idx + 2 < m) v2 = deg[idx + 2];
    if (idx + 3 < m) v3 = deg[idx + 3];
    const int tsum = v0 + v1 + v2 + v3;
    sd[tid] = tsum;
    __syncthreads();
    for (int off = 1; off < 256; off <<= 1) {
        int t = (tid >= off) ? sd[tid - off] : 0;
        __syncthreads();
        sd[tid] += t;
        __syncthreads();
    }
    const int texcl = sd[tid] - tsum;
    if (tid == 255) partials[blockIdx.x] = sd[255];
    if (idx     < m) excl[idx]     = texcl;
    if (idx + 1 < m) excl[idx + 1] = texcl + v0;
    if (idx + 2 < m) excl[idx + 2] = texcl + v0 + v1;
    if (idx + 3 < m) excl[idx + 3] = texcl + v0 + v1 + v2;
}

__global__ __launch_bounds__(512) void k_scan2(int* __restrict__ partials, int nb) {
    __shared__ int sd[512];
    const int tid = threadIdx.x;
    const int v = (tid < nb) ? partials[tid] : 0;
    sd[tid] = v;
    __syncthreads();
    for (int off = 1; off < 512; off <<= 1) {
        int t = (tid >= off) ? sd[tid - off] : 0;
        __syncthreads();
        sd[tid] += t;
        __syncthreads();
    }
    if (tid < nb) partials[tid] = sd[tid] - v;  // exclusive
}

// ---------------------------------------------------------------------------
// P2: partition edges into coarse buckets via LDS cursors (scan offsets
// materialized here: cnt[idx] + partials[idx>>10]).
// dst entry: (dst&255)<<17 | src (25 bits); src entry: src&255.
// ---------------------------------------------------------------------------
__global__ __launch_bounds__(256) void k_part(const int* __restrict__ src,
                                              const int* __restrict__ dst,
                                              const int* __restrict__ cnt,
                                              const int* __restrict__ partials,
                                              unsigned* __restrict__ tmp,
                                              int nb, int ne) {
    __shared__ int cD[512], cS[512];
    const int blk = blockIdx.x, tid = threadIdx.x;
    for (int bb = tid; bb < nb; bb += 256) {
        int iD = bb * BLK1 + blk;
        int iS = (nb + bb) * BLK1 + blk;
        cD[bb] = cnt[iD] + partials[iD >> 10];
        cS[bb] = cnt[iS] + partials[iS >> 10];
    }
    __syncthreads();
    const int epb = (ne + BLK1 - 1) / BLK1;
    const int e0 = blk * epb, e1 = min(ne, e0 + epb);
    for (int e = e0 + tid; e < e1; e += 256) {
        int d = dst[e], s = src[e];
        int pD = atomicAdd(&cD[d >> 8], 1);
        tmp[pD] = ((unsigned)(d & 255) << 17) | (unsigned)s;
        int pS = atomicAdd(&cS[s >> 8], 1);
        tmp[pS] = (unsigned)(s & 255);
    }
}

// ---------------------------------------------------------------------------
// P3-dst: one block per bucket. LDS 256-bin histogram -> deg_in + row_ptr
// (bucket base + LDS exclusive scan), then LDS-cursor scatter -> src_sorted.
// ---------------------------------------------------------------------------
__global__ __launch_bounds__(256) void k_fine_dst(const int* __restrict__ cnt,
                                                  const int* __restrict__ partials,
                                                  const unsigned* __restrict__ tmp,
                                                  int* __restrict__ src_sorted,
                                                  int* __restrict__ deg_in,
                                                  int* __restrict__ row_ptr,
                                                  int n, int nb, int ne) {
    __shared__ int hist[256], sd[256], cur[256];
    const int b = blockIdx.x, tid = threadIdx.x;
    const int ib = b * BLK1;
    const int base = cnt[ib] + partials[ib >> 10];
    const int ie = (b + 1) * BLK1;
    const int end = (b + 1 < nb) ? (cnt[ie] + partials[ie >> 10]) : ne;
    hist[tid] = 0;
    __syncthreads();
    for (int i = base + tid; i < end; i += 256)
        atomicAdd(&hist[tmp[i] >> 17], 1);
    __syncthreads();
    const int deg = hist[tid];
    sd[tid] = deg;
    __syncthreads();
    for (int off = 1; off < 256; off <<= 1) {
        int t = (tid >= off) ? sd[tid - off] : 0;
        __syncthreads();
        sd[tid] += t;
        __syncthreads();
    }
    const int excl = sd[tid] - deg;
    cur[tid] = excl;
    const int node = b * 256 + tid;
    if (node < n) { deg_in[node] = deg; row_ptr[node] = base + excl; }
    __syncthreads();
    for (int i = base + tid; i < end; i += 256) {
        unsigned v = tmp[i];
        int pos = base + atomicAdd(&cur[v >> 17], 1);
        src_sorted[pos] = (int)(v & 0x1FFFFu);
    }
}

// ---------------------------------------------------------------------------
// P3-src: one block per bucket. LDS histogram of src entries -> deg_out.
// ---------------------------------------------------------------------------
__global__ __launch_bounds__(256) void k_fine_src(const int* __restrict__ cnt,
                                                  const int* __restrict__ partials,
                                                  const unsigned* __restrict__ tmp,
                                                  int* __restrict__ deg_out,
                                                  int n, int nb, int ne) {
    __shared__ int hist[256];
    const int b = blockIdx.x, tid = threadIdx.x;
    const int ib = (nb + b) * BLK1;
    const int base = cnt[ib] + partials[ib >> 10];
    const int ie = (nb + b + 1) * BLK1;
    const int end = (b + 1 < nb) ? (cnt[ie] + partials[ie >> 10]) : 2 * ne;
    hist[tid] = 0;
    __syncthreads();
    for (int i = base + tid; i < end; i += 256)
        atomicAdd(&hist[tmp[i] & 255u], 1);
    __syncthreads();
    const int node = b * 256 + tid;
    if (node < n) deg_out[node] = hist[tid];
}

// ---------------------------------------------------------------------------
// GEMM: h(bf16) = diag(rsqrt(max(deg_out,1))) * X * W, 16x16x32 bf16 MFMA.
// A-fragments straight from global, scaled+converted in-register; W^T (32 KB
// bf16, XOR-swizzled) in LDS, staged once per block, 2 row-tiles of 64.
// ---------------------------------------------------------------------------
__global__ __launch_bounds__(256, 4) void k_gemm(const float* __restrict__ x,
                                                 const float* __restrict__ W,
                                                 const int* __restrict__ deg_out,
                                                 unsigned short* __restrict__ h, int n) {
    __shared__ char lds[32768];
    const int tid = threadIdx.x;
    const int lane = tid & 63;
    const int wid = tid >> 6;

    {
        const int f = tid & 63;
        const int kg = (tid >> 6) * 64;
        const int swz = (f & 7) << 4;
#pragma unroll
        for (int j = 0; j < 16; ++j) {
            const int k0 = kg + j * 4;
            unsigned u0 = bf16_rne(W[(k0 + 0) * OUT_F + f]);
            unsigned u1 = bf16_rne(W[(k0 + 1) * OUT_F + f]);
            unsigned u2 = bf16_rne(W[(k0 + 2) * OUT_F + f]);
            unsigned u3 = bf16_rne(W[(k0 + 3) * OUT_F + f]);
            uint2 p;
            p.x = u0 | (u1 << 16);
            p.y = u2 | (u3 << 16);
            int byte = f * 512 + ((k0 * 2) ^ swz);
            *(uint2*)(lds + byte) = p;
        }
    }
    __syncthreads();

    const int r15 = lane & 15;           // A row within 16 / B col within 16
    const int q = lane >> 4;             // k-quarter
    const int bswz = (r15 & 7) << 4;
    const int b_base = r15 * 512;
    const int rq = q * 4;

#pragma unroll
    for (int p = 0; p < 2; ++p) {
        const int row = blockIdx.x * 128 + p * 64 + wid * 16 + r15;
        const int rowc = min(row, n - 1);                  // clamp (stores guarded)
        const float s = rsqrtf(fmaxf((float)deg_out[rowc], 1.0f));
        const float* xr = x + (size_t)rowc * IN_F + q * 8;

        f32x4 acc0 = {0.f, 0.f, 0.f, 0.f};
        f32x4 acc1 = acc0, acc2 = acc0, acc3 = acc0;

#pragma unroll
        for (int kk = 0; kk < 8; ++kk) {
            float4 a0 = *(const float4*)(xr + kk * 32);
            float4 a1 = *(const float4*)(xr + kk * 32 + 4);
            s16x8 a;
            a[0] = (short)bf16_rne(a0.x * s);
            a[1] = (short)bf16_rne(a0.y * s);
            a[2] = (short)bf16_rne(a0.z * s);
            a[3] = (short)bf16_rne(a0.w * s);
            a[4] = (short)bf16_rne(a1.x * s);
            a[5] = (short)bf16_rne(a1.y * s);
            a[6] = (short)bf16_rne(a1.z * s);
            a[7] = (short)bf16_rne(a1.w * s);
            const int off = (q * 16 + kk * 64) ^ bswz;     // XOR in bits 4-6: carry-free
            s16x8 b0 = *(const s16x8*)(lds + b_base + off);
            s16x8 b1 = *(const s16x8*)(lds + b_base + 8192 + off);
            s16x8 b2 = *(const s16x8*)(lds + b_base + 16384 + off);
            s16x8 b3 = *(const s16x8*)(lds + b_base + 24576 + off);
            acc0 = __builtin_amdgcn_mfma_f32_16x16x32_bf16(a, b0, acc0, 0, 0, 0);
            acc1 = __builtin_amdgcn_mfma_f32_16x16x32_bf16(a, b1, acc1, 0, 0, 0);
            acc2 = __builtin_amdgcn_mfma_f32_16x16x32_bf16(a, b2, acc2, 0, 0, 0);
            acc3 = __builtin_amdgcn_mfma_f32_16x16x32_bf16(a, b3, acc3, 0, 0, 0);
        }

        // D layout: row=(lane>>4)*4+j, col=lane&15 (m89-verified)
#pragma unroll
        for (int j = 0; j < 4; ++j) {
            const int grow = blockIdx.x * 128 + p * 64 + wid * 16 + rq + j;
            if (grow < n) {
                unsigned short* hp = h + (size_t)grow * OUT_F + r15;
                hp[0]  = bf16_rne(acc0[j]);
                hp[16] = bf16_rne(acc1[j]);
                hp[32] = bf16_rne(acc2[j]);
                hp[48] = bf16_rne(acc3[j]);
            }
        }
    }
}

// ---------------------------------------------------------------------------
// CSR gather-aggregate v2: wave per node, 2 edges per step (half-waves),
// dword (2-feat) gathers, 4-edge unroll = 2 independent load chains.
// Cross-half shfl_xor reduce, lanes 0-31 write coalesced float2.
// ---------------------------------------------------------------------------
__global__ __launch_bounds__(256) void k_aggregate(const int* __restrict__ row_ptr,
                                                   const int* __restrict__ deg_in,
                                                   const int* __restrict__ src_sorted,
                                                   const unsigned* __restrict__ h32,
                                                   const float* __restrict__ b,
                                                   float* __restrict__ out, int n) {
    const int node = __builtin_amdgcn_readfirstlane(blockIdx.x * 4 + (threadIdx.x >> 6));
    if (node >= n) return;
    const int lane = threadIdx.x & 63;
    const int f2 = lane & 31;            // feat pair: feats 2*f2, 2*f2+1
    const int half = lane >> 5;          // edge selector within a step
    const int start = row_ptr[node];
    const int deg = deg_in[node];

    float a0 = 0.f, a1 = 0.f, c0 = 0.f, c1 = 0.f;
    int i = 0;
    const int deg4 = deg & ~3;
    for (; i < deg4; i += 4) {
        int s0 = src_sorted[start + i + half];
        int s1 = src_sorted[start + i + 2 + half];
        unsigned u0 = h32[s0 * 32 + f2];
        unsigned u1 = h32[s1 * 32 + f2];
        a0 += bf16_lo(u0); a1 += bf16_hi(u0);
        c0 += bf16_lo(u1); c1 += bf16_hi(u1);
    }
    for (; i < deg; i += 2) {            // tail: up to 3 edges, predicated
        const int e = i + half;
        const bool v = e < deg;
        int s = src_sorted[start + (v ? e : i)];
        unsigned u = h32[s * 32 + f2];
        if (v) { a0 += bf16_lo(u); a1 += bf16_hi(u); }
    }
    a0 += c0; a1 += c1;
    a0 += __shfl_xor(a0, 32, 64);
    a1 += __shfl_xor(a1, 32, 64);

    if (half == 0) {
        const float scale = rsqrtf(fmaxf((float)deg, 1.0f));
        float2 v;
        v.x = a0 * scale + b[f2 * 2];
        v.y = a1 * scale + b[f2 * 2 + 1];
        *(float2*)&out[(size_t)node * OUT_F + f2 * 2] = v;
    }
}

extern "C" void kernel_launch(void* const* d_in, const int* in_sizes, int n_in,
                              void* d_out, int out_size, void* d_ws, size_t ws_size,
                              hipStream_t stream) {
    const float* x   = (const float*)d_in[0];
    const int*   src = (const int*)d_in[1];
    const int*   dst = (const int*)d_in[2];
    const float* W   = (const float*)d_in[3];
    const float* b   = (const float*)d_in[4];
    float* out = (float*)d_out;

    const int n  = in_sizes[0] / IN_F;   // 100000
    const int ne = in_sizes[1];          // 1000000

    const int nb = (n + 255) >> 8;       // 391 coarse buckets (<= 512)
    const int m  = 2 * nb * BLK1;        // cnt matrix size (400384)

    int* cnt        = (int*)d_ws;                 // m
    int* partials   = cnt + m;                    // 512
    unsigned* tmp   = (unsigned*)(partials + 512);// 2*ne
    int* src_sorted = (int*)(tmp + 2 * (size_t)ne); // ne
    int* deg_in     = src_sorted + ne;            // n
    int* deg_out    = deg_in + n;                 // n
    int* row_ptr    = deg_out + n;                // n
    unsigned short* h = (unsigned short*)(row_ptr + n);  // n*64 bf16

    const int nb_scan = (m + 1023) / 1024;        // 391 (<= 512)

    k_coarse<<<BLK1, 256, 0, stream>>>(src, dst, cnt, nb, ne);
    k_scan1<<<nb_scan, 256, 0, stream>>>(cnt, cnt, partials, m);
    k_scan2<<<1, 512, 0, stream>>>(partials, nb_scan);
    k_part<<<BLK1, 256, 0, stream>>>(src, dst, cnt, partials, tmp, nb, ne);
    k_fine_dst<<<nb, 256, 0, stream>>>(cnt, partials, tmp, src_sorted, deg_in, row_ptr, n, nb, ne);
    k_fine_src<<<nb, 256, 0, stream>>>(cnt, partials, tmp, deg_out, n, nb, ne);
    k_gemm<<<(n + 127) / 128, 256, 0, stream>>>(x, W, deg_out, h, n);
    k_aggregate<<<(n + 3) / 4, 256, 0, stream>>>(row_ptr, deg_in, src_sorted,
                                                 (const unsigned*)h, b, out, n);
}